// Round 4
// baseline (261.965 us; speedup 1.0000x reference)
//
#include <hip/hip_runtime.h>
#include <math.h>

// Problem constants (from reference): B=8, N_INST=64, H=W=480
#define HW      (480 * 480)     // 230400 pixels per plane
#define HW4     (HW / 4)        // 57600 float4 per plane
#define NINST   64
#define NB      8               // batch
#define NV      9               // reduced: mask, q0..3, s0..2, z
#define GI      4               // instances processed together (register acc)
#define NBLK    128             // blocks per sample (grid.x)
#define THREADS 256

__device__ __forceinline__ float dot4(const float4 a, const float4 b) {
    return (a.x * b.x + a.y * b.y) + (a.z * b.z + a.w * b.w);
}

// Grid = (NBLK, NB). Each block: build the list of instances with sid==b
// (once, in LDS), then for each group of up to GI instances keep GI*NV
// per-thread register accumulators and stream the block's chunk range with
// NO barriers: 4 mask loads + 10 plane loads + 8 xy stores + dots, all
// independent -> fully pipelined. One shuffle-reduce per group (not per
// chunk). part[n][bx][v] written exactly once per (n, bx).
__global__ __launch_bounds__(THREADS) void agg_main(
    const float* __restrict__ masks,   // [N,H,W]
    const int*   __restrict__ sids,    // [N]
    const float* __restrict__ quat,    // [B,4,H,W]
    const float* __restrict__ scales,  // [B,3,H,W]
    const float* __restrict__ xy,      // [B,2,H,W]
    const float* __restrict__ z,       // [B,H,W]
    float*       __restrict__ out,     // xy_masked lives at out+512
    float*       __restrict__ part)    // [NINST][NBLK][NV]
{
    const int tid = threadIdx.x;
    const int bx  = blockIdx.x;                    // chunk-range id
    const int b   = blockIdx.y;                    // sample

    __shared__ int   ilist[NINST];
    __shared__ int   scnt;
    __shared__ float sred[4][GI * NV];

    if (tid == 0) {
        int c = 0;
        for (int n = 0; n < NINST; ++n)
            if (sids[n] == b) ilist[c++] = n;
        scnt = c;
    }
    __syncthreads();
    const int cnt = scnt;

    const float4* M  = (const float4*)masks;
    const float4* Q  = (const float4*)quat   + (size_t)b * 4 * HW4;
    const float4* S  = (const float4*)scales + (size_t)b * 3 * HW4;
    const float4* X  = (const float4*)xy     + (size_t)b * 2 * HW4;
    const float4* Zp = (const float4*)z      + (size_t)b * HW4;
    float4*       O  = (float4*)(out + 512);

    const int lane = tid & 63;
    const int wid  = tid >> 6;

    for (int g0 = 0; g0 < cnt; g0 += GI) {
        int  nidx[GI];
        bool valid[GI];
#pragma unroll
        for (int j = 0; j < GI; ++j) {
            valid[j] = (g0 + j < cnt);
            nidx[j]  = ilist[valid[j] ? (g0 + j) : (cnt - 1)];
        }

        float acc[GI][NV];
#pragma unroll
        for (int j = 0; j < GI; ++j)
#pragma unroll
            for (int v = 0; v < NV; ++v) acc[j][v] = 0.0f;

        for (int i = bx * THREADS + tid; i < HW4; i += NBLK * THREADS) {
            float4 m[GI];
#pragma unroll
            for (int j = 0; j < GI; ++j)
                m[j] = M[(size_t)nidx[j] * HW4 + i];

            const float4 vx0 = X[i];
            const float4 vx1 = X[HW4 + i];
#pragma unroll
            for (int j = 0; j < GI; ++j) {
                if (valid[j]) {  // block-uniform branch
                    O[((size_t)nidx[j] * 2 + 0) * HW4 + i] = make_float4(
                        m[j].x * vx0.x, m[j].y * vx0.y, m[j].z * vx0.z, m[j].w * vx0.w);
                    O[((size_t)nidx[j] * 2 + 1) * HW4 + i] = make_float4(
                        m[j].x * vx1.x, m[j].y * vx1.y, m[j].z * vx1.z, m[j].w * vx1.w);
                }
            }

#pragma unroll
            for (int j = 0; j < GI; ++j)
                acc[j][0] += (m[j].x + m[j].y) + (m[j].z + m[j].w);

            float4 t;
            t = Q[0 * HW4 + i];
#pragma unroll
            for (int j = 0; j < GI; ++j) acc[j][1] += dot4(m[j], t);
            t = Q[1 * HW4 + i];
#pragma unroll
            for (int j = 0; j < GI; ++j) acc[j][2] += dot4(m[j], t);
            t = Q[2 * HW4 + i];
#pragma unroll
            for (int j = 0; j < GI; ++j) acc[j][3] += dot4(m[j], t);
            t = Q[3 * HW4 + i];
#pragma unroll
            for (int j = 0; j < GI; ++j) acc[j][4] += dot4(m[j], t);
            t = S[0 * HW4 + i];
#pragma unroll
            for (int j = 0; j < GI; ++j) acc[j][5] += dot4(m[j], t);
            t = S[1 * HW4 + i];
#pragma unroll
            for (int j = 0; j < GI; ++j) acc[j][6] += dot4(m[j], t);
            t = S[2 * HW4 + i];
#pragma unroll
            for (int j = 0; j < GI; ++j) acc[j][7] += dot4(m[j], t);
            t = Zp[i];
#pragma unroll
            for (int j = 0; j < GI; ++j) acc[j][8] += dot4(m[j], t);
        }

        // one reduce per group: wave64 shuffle, then cross-wave via LDS
#pragma unroll
        for (int j = 0; j < GI; ++j)
#pragma unroll
            for (int v = 0; v < NV; ++v) {
                float x = acc[j][v];
#pragma unroll
                for (int off = 32; off > 0; off >>= 1)
                    x += __shfl_down(x, off, 64);
                if (lane == 0) sred[wid][j * NV + v] = x;
            }
        __syncthreads();
        if (tid < GI * NV) {
            const int j = tid / NV;
            const int v = tid - j * NV;
            if (g0 + j < cnt) {
                const int n = ilist[g0 + j];
                part[((size_t)n * NBLK + bx) * NV + v] =
                    (sred[0][tid] + sred[1][tid]) + (sred[2][tid] + sred[3][tid]);
            }
        }
        __syncthreads();                            // sred reused next group
    }
}

// Finalize: one block per instance; sum NBLK partials, compute means,
// L2-normalize q, exp(z mean), write the 512 aggregate floats.
__global__ __launch_bounds__(THREADS) void agg_final(
    const float* __restrict__ part,    // [NINST][NBLK][NV]
    float*       __restrict__ out)
{
    const int n   = blockIdx.x;
    const int tid = threadIdx.x;

    float vals[NV];
#pragma unroll
    for (int v = 0; v < NV; ++v) vals[v] = 0.0f;
    for (int c = tid; c < NBLK; c += THREADS) {
        const float* p = part + ((size_t)n * NBLK + c) * NV;
#pragma unroll
        for (int v = 0; v < NV; ++v) vals[v] += p[v];
    }

    __shared__ float sred[4][NV];
    const int lane = tid & 63;
    const int wid  = tid >> 6;
#pragma unroll
    for (int v = 0; v < NV; ++v) {
        float x = vals[v];
#pragma unroll
        for (int off = 32; off > 0; off >>= 1)
            x += __shfl_down(x, off, 64);
        if (lane == 0) sred[wid][v] = x;
    }
    __syncthreads();

    if (tid == 0) {
        float s[NV];
#pragma unroll
        for (int v = 0; v < NV; ++v)
            s[v] = (sred[0][v] + sred[1][v]) + (sred[2][v] + sred[3][v]);

        const float inv = 1.0f / s[0];             // 1 / mask_size
        const float q0 = s[1] * inv, q1 = s[2] * inv, q2 = s[3] * inv, q3 = s[4] * inv;
        const float norm = sqrtf(q0 * q0 + q1 * q1 + q2 * q2 + q3 * q3);
        const float d = fmaxf(norm, 1e-12f);
        out[n * 4 + 0] = q0 / d;
        out[n * 4 + 1] = q1 / d;
        out[n * 4 + 2] = q2 / d;
        out[n * 4 + 3] = q3 / d;

        out[256 + n * 3 + 0] = s[5] * inv;
        out[256 + n * 3 + 1] = s[6] * inv;
        out[256 + n * 3 + 2] = s[7] * inv;

        out[448 + n] = expf(s[8] * inv);
    }
}

extern "C" void kernel_launch(void* const* d_in, const int* in_sizes, int n_in,
                              void* d_out, int out_size, void* d_ws, size_t ws_size,
                              hipStream_t stream) {
    const float* masks  = (const float*)d_in[0];   // [64,480,480]
    const int*   sids   = (const int*)d_in[1];     // [64]
    const float* quat   = (const float*)d_in[2];   // [8,4,480,480]
    const float* scales = (const float*)d_in[3];   // [8,3,480,480]
    const float* xy     = (const float*)d_in[4];   // [8,2,480,480]
    const float* z      = (const float*)d_in[5];   // [8,480,480]
    float* out  = (float*)d_out;
    float* part = (float*)d_ws;                    // 64*128*9*4 B = 294912 B

    dim3 grid(NBLK, NB);
    agg_main<<<grid, THREADS, 0, stream>>>(masks, sids, quat, scales, xy, z, out, part);
    agg_final<<<NINST, THREADS, 0, stream>>>(part, out);
}

// Round 5
// 245.735 us; speedup vs baseline: 1.0660x; 1.0660x over previous
//
#include <hip/hip_runtime.h>
#include <math.h>

// Problem constants (from reference): B=8, N_INST=64, H=W=480
#define HW      (480 * 480)     // 230400 pixels per plane
#define HW4     (HW / 4)        // 57600 float4 per plane
#define NINST   64
#define NB      8               // batch
#define NV      9               // reduced: mask, q0..3, s0..2, z
#define GI      8               // instances per group (register accumulators)
#define NBLK    225             // blocks per sample: NBLK*THREADS == HW4 exactly
#define THREADS 256

__device__ __forceinline__ float dot4(const float4 a, const float4 b) {
    return (a.x * b.x + a.y * b.y) + (a.z * b.z + a.w * b.w);
}

// Wave64 sum on the VALU pipe via DPP (rocPRIM idiom): row_shr 1/2/4/8 then
// row_bcast:15, row_bcast:31. Result valid in lane 63. No DS-pipe usage.
template <int CTRL>
__device__ __forceinline__ float dpp_add(float x) {
    int s = __builtin_amdgcn_update_dpp(0, __float_as_int(x), CTRL, 0xf, 0xf, false);
    return x + __int_as_float(s);
}
__device__ __forceinline__ float wave_sum(float x) {
    x = dpp_add<0x111>(x);   // row_shr:1
    x = dpp_add<0x112>(x);   // row_shr:2
    x = dpp_add<0x114>(x);   // row_shr:4
    x = dpp_add<0x118>(x);   // row_shr:8  -> lanes 15/31/47/63 hold row sums
    x = dpp_add<0x142>(x);   // row_bcast:15 -> lane31 = 0..31, lane63 = 32..63
    x = dpp_add<0x143>(x);   // row_bcast:31 -> lane63 = 0..63
    return x;                // total in lane 63
}

// Grid = (NBLK, NB). One float4 column per thread (perfect tiling, no loop,
// no barriers in the hot path). Load the sample's 10 shared planes once into
// registers; process all instances of the sample in groups of GI=8 with
// 72 register accumulators; DPP wave-reduce once per group; tiny LDS combine
// across the 4 waves at the end. part[n][bx][v] written exactly once.
__global__ __launch_bounds__(THREADS) void agg_main(
    const float* __restrict__ masks,   // [N,H,W]
    const int*   __restrict__ sids,    // [N]
    const float* __restrict__ quat,    // [B,4,H,W]
    const float* __restrict__ scales,  // [B,3,H,W]
    const float* __restrict__ xy,      // [B,2,H,W]
    const float* __restrict__ z,       // [B,H,W]
    float*       __restrict__ out,     // xy_masked lives at out+512
    float*       __restrict__ part)    // [NINST][NBLK][NV]
{
    const int tid = threadIdx.x;
    const int bx  = blockIdx.x;                    // column-block id
    const int b   = blockIdx.y;                    // sample
    const int i   = bx * THREADS + tid;            // float4 index in a plane

    __shared__ int   ilist[NINST];
    __shared__ int   scnt;
    __shared__ float swred[4][GI * NV];

    if (tid == 0) {
        int c = 0;
        for (int n = 0; n < NINST; ++n)
            if (sids[n] == b) ilist[c++] = n;
        scnt = c;
    }
    __syncthreads();
    const int cnt = scnt;

    const float4* M  = (const float4*)masks;
    const float4* Q  = (const float4*)quat   + (size_t)b * 4 * HW4;
    const float4* S  = (const float4*)scales + (size_t)b * 3 * HW4;
    const float4* X  = (const float4*)xy     + (size_t)b * 2 * HW4;
    const float4* Zp = (const float4*)z      + (size_t)b * HW4;
    float4*       O  = (float4*)(out + 512);

    // Shared planes for this column -> registers (10 x float4), live across
    // all instance groups (never re-read from memory).
    const float4 vq0 = Q[0 * HW4 + i];
    const float4 vq1 = Q[1 * HW4 + i];
    const float4 vq2 = Q[2 * HW4 + i];
    const float4 vq3 = Q[3 * HW4 + i];
    const float4 vs0 = S[0 * HW4 + i];
    const float4 vs1 = S[1 * HW4 + i];
    const float4 vs2 = S[2 * HW4 + i];
    const float4 vx0 = X[0 * HW4 + i];
    const float4 vx1 = X[1 * HW4 + i];
    const float4 vz  = Zp[i];

    const int lane = tid & 63;
    const int wid  = tid >> 6;

    for (int g0 = 0; g0 < cnt; g0 += GI) {
        int  nidx[GI];
        bool valid[GI];
#pragma unroll
        for (int j = 0; j < GI; ++j) {
            valid[j] = (g0 + j < cnt);
            nidx[j]  = ilist[valid[j] ? (g0 + j) : (cnt - 1)];
        }

        // mask loads (clamped for invalid slots; their accs are never written)
        float4 m[GI];
#pragma unroll
        for (int j = 0; j < GI; ++j)
            m[j] = M[(size_t)nidx[j] * HW4 + i];

        // dense masked xy output (block-uniform guard)
#pragma unroll
        for (int j = 0; j < GI; ++j) {
            if (valid[j]) {
                O[((size_t)nidx[j] * 2 + 0) * HW4 + i] = make_float4(
                    m[j].x * vx0.x, m[j].y * vx0.y, m[j].z * vx0.z, m[j].w * vx0.w);
                O[((size_t)nidx[j] * 2 + 1) * HW4 + i] = make_float4(
                    m[j].x * vx1.x, m[j].y * vx1.y, m[j].z * vx1.z, m[j].w * vx1.w);
            }
        }

        // 72 per-thread partial sums
        float acc[GI][NV];
#pragma unroll
        for (int j = 0; j < GI; ++j) {
            acc[j][0] = (m[j].x + m[j].y) + (m[j].z + m[j].w);
            acc[j][1] = dot4(m[j], vq0);
            acc[j][2] = dot4(m[j], vq1);
            acc[j][3] = dot4(m[j], vq2);
            acc[j][4] = dot4(m[j], vq3);
            acc[j][5] = dot4(m[j], vs0);
            acc[j][6] = dot4(m[j], vs1);
            acc[j][7] = dot4(m[j], vs2);
            acc[j][8] = dot4(m[j], vz);
        }

        // VALU-pipe wave reduce; lane 63 stores wave totals to LDS
#pragma unroll
        for (int j = 0; j < GI; ++j)
#pragma unroll
            for (int v = 0; v < NV; ++v) {
                const float t = wave_sum(acc[j][v]);
                if (lane == 63) swred[wid][j * NV + v] = t;
            }
        __syncthreads();
        if (tid < GI * NV) {
            const int j = tid / NV;
            const int v = tid - j * NV;
            if (g0 + j < cnt) {
                const int n = ilist[g0 + j];
                part[((size_t)n * NBLK + bx) * NV + v] =
                    (swred[0][tid] + swred[1][tid]) + (swred[2][tid] + swred[3][tid]);
            }
        }
        __syncthreads();                            // swred reused next group
    }
}

// Finalize: one block per instance; sum NBLK partials, compute means,
// L2-normalize q, exp(z mean), write the 512 aggregate floats.
__global__ __launch_bounds__(THREADS) void agg_final(
    const float* __restrict__ part,    // [NINST][NBLK][NV]
    float*       __restrict__ out)
{
    const int n   = blockIdx.x;
    const int tid = threadIdx.x;

    float vals[NV];
#pragma unroll
    for (int v = 0; v < NV; ++v) vals[v] = 0.0f;
    for (int c = tid; c < NBLK; c += THREADS) {
        const float* p = part + ((size_t)n * NBLK + c) * NV;
#pragma unroll
        for (int v = 0; v < NV; ++v) vals[v] += p[v];
    }

    __shared__ float sred[4][NV];
    const int lane = tid & 63;
    const int wid  = tid >> 6;
#pragma unroll
    for (int v = 0; v < NV; ++v) {
        float x = vals[v];
#pragma unroll
        for (int off = 32; off > 0; off >>= 1)
            x += __shfl_down(x, off, 64);
        if (lane == 0) sred[wid][v] = x;
    }
    __syncthreads();

    if (tid == 0) {
        float s[NV];
#pragma unroll
        for (int v = 0; v < NV; ++v)
            s[v] = (sred[0][v] + sred[1][v]) + (sred[2][v] + sred[3][v]);

        const float inv = 1.0f / s[0];             // 1 / mask_size
        const float q0 = s[1] * inv, q1 = s[2] * inv, q2 = s[3] * inv, q3 = s[4] * inv;
        const float norm = sqrtf(q0 * q0 + q1 * q1 + q2 * q2 + q3 * q3);
        const float d = fmaxf(norm, 1e-12f);
        out[n * 4 + 0] = q0 / d;
        out[n * 4 + 1] = q1 / d;
        out[n * 4 + 2] = q2 / d;
        out[n * 4 + 3] = q3 / d;

        out[256 + n * 3 + 0] = s[5] * inv;
        out[256 + n * 3 + 1] = s[6] * inv;
        out[256 + n * 3 + 2] = s[7] * inv;

        out[448 + n] = expf(s[8] * inv);
    }
}

extern "C" void kernel_launch(void* const* d_in, const int* in_sizes, int n_in,
                              void* d_out, int out_size, void* d_ws, size_t ws_size,
                              hipStream_t stream) {
    const float* masks  = (const float*)d_in[0];   // [64,480,480]
    const int*   sids   = (const int*)d_in[1];     // [64]
    const float* quat   = (const float*)d_in[2];   // [8,4,480,480]
    const float* scales = (const float*)d_in[3];   // [8,3,480,480]
    const float* xy     = (const float*)d_in[4];   // [8,2,480,480]
    const float* z      = (const float*)d_in[5];   // [8,480,480]
    float* out  = (float*)d_out;
    float* part = (float*)d_ws;                    // 64*225*9*4 B = 518400 B

    dim3 grid(NBLK, NB);
    agg_main<<<grid, THREADS, 0, stream>>>(masks, sids, quat, scales, xy, z, out, part);
    agg_final<<<NINST, THREADS, 0, stream>>>(part, out);
}